// Round 22
// baseline (318.059 us; speedup 1.0000x reference)
//
#include <hip/hip_runtime.h>

#define N      2048
#define HALO   10            // sweeps fused per launch
#define SWP    10
#define WX     128           // window width (16 chunks x 8 cols)
#define WY     96            // window rows  (24 bands x 4 rows)
#define TX     108           // output tile width
#define TY     76            // output tile height
#define NTX    19            // last tile clamped; overlap writes identical values
#define NTY    27
#define NTHR   384           // 24 bands x 16 chunks
#define NB     24            // bands of 4 rows
#define PS     132           // LDS boundary row stride (words)
#define BUFW   (2*NB*PS)     // one slab: 6336 words; two slabs = 50.7 KB
// XCD swizzle (bijective, m204 form): NWG=513, q=64, r=1 -> XCD0 owns 65
// consecutive tile-ids, XCD1..7 own 64. Same mapping every launch => each
// XCD re-reads its own previous writes from its own L2.
#define NWGQ   64
#define NWGR   1

__device__ __forceinline__ float bump(float xv, float yv) {
    float dx = xv - 0.5f, dy = yv - 0.5f;
    return expf(-50.f * (dx * dx + dy * dy));
}

__device__ __forceinline__ int swz_wgid(int bid) {
    int xcd = bid & 7;
    int j   = bid >> 3;
    int start = (xcd < NWGR) ? xcd * (NWGQ + 1)
                             : NWGR * (NWGQ + 1) + (xcd - NWGR) * NWGQ;
    return start + j;
}

// Register-resident fused sweeps (R18 structure, taller window): each thread
// owns a 4x8 patch; LDS ping-pong slabs hold only band-boundary rows ->
// 1 barrier/sweep. Contamination advances 1 cell/sweep; stored cells sit at
// window distance >= HALO -> exact. Kernels duplicated verbatim (no shared
// __device__ fn) to avoid R8/R9 cross-instantiation regalloc coupling.
// R20 note: >=12 waves/CU needed to hide LDS/global latency.

// ---- first launch: init fused (patch = exp bump from X,Y), then 10 sweeps ----
__global__ __launch_bounds__(NTHR) void jm_sweep0(const float* __restrict__ X,
                                                  const float* __restrict__ Y,
                                                  float* __restrict__ out) {
    __shared__ float bnd[2 * BUFW];
    const int wgid = swz_wgid(blockIdx.x);
    const int bx = wgid % NTX;
    const int by = wgid / NTX;
    const int ox = (bx < NTX - 1) ? bx * TX : (N - TX);
    const int oy = (by < NTY - 1) ? by * TY : (N - TY);
    const int gx0 = ox - HALO, gy0 = oy - HALO;
    const int t = threadIdx.x;
    const int c = t & 15;
    const int g = t >> 4;
    const int colb = gx0 + 8 * c;

    float f[8];
    #pragma unroll
    for (int j = 0; j < 8; ++j)
        f[j] = (colb + j >= 1 && colb + j <= N - 2) ? 0.25f : 0.f;
    float rm[4];
    #pragma unroll
    for (int k = 0; k < 4; ++k) {
        int gr = gy0 + 4 * g + k;
        rm[k] = (gr >= 1 && gr <= N - 2) ? 1.f : 0.f;
    }

    // ---- init patch directly from X,Y (out-of-domain -> 0) ----
    float4 pA[4], pB[4];
    #pragma unroll
    for (int k = 0; k < 4; ++k) {
        int gr = gy0 + 4 * g + k;
        float4 a = make_float4(0.f, 0.f, 0.f, 0.f), b = a;
        if (gr >= 0 && gr < N) {
            const float* xr = X + (long)gr * N;
            const float* yr = Y + (long)gr * N;
            if (colb >= 0 && colb + 7 < N) {
                float4 x0 = *(const float4*)(xr + colb);
                float4 x1 = *(const float4*)(xr + colb + 4);
                float4 y0 = *(const float4*)(yr + colb);
                float4 y1 = *(const float4*)(yr + colb + 4);
                a.x = bump(x0.x, y0.x); a.y = bump(x0.y, y0.y);
                a.z = bump(x0.z, y0.z); a.w = bump(x0.w, y0.w);
                b.x = bump(x1.x, y1.x); b.y = bump(x1.y, y1.y);
                b.z = bump(x1.z, y1.z); b.w = bump(x1.w, y1.w);
            } else {
                float v[8];
                #pragma unroll
                for (int j = 0; j < 8; ++j) {
                    int gc = colb + j;
                    v[j] = (gc >= 0 && gc < N) ? bump(xr[gc], yr[gc]) : 0.f;
                }
                a = make_float4(v[0], v[1], v[2], v[3]);
                b = make_float4(v[4], v[5], v[6], v[7]);
            }
        }
        pA[k] = a; pB[k] = b;
    }

    const int co = 8 * c;
    const int wT = (NB + g) * PS + co;
    const int wB = g * PS + co;
    const int rU = ((g > 0) ? (g - 1) : 0) * PS + co;
    const int rD = (NB + ((g < NB - 1) ? (g + 1) : g)) * PS + co;

    for (int s = 0; s < SWP; ++s) {
        float* buf = bnd + (s & 1) * BUFW;
        *(float4*)(buf + wT)     = pA[0];
        *(float4*)(buf + wT + 4) = pB[0];
        *(float4*)(buf + wB)     = pA[3];
        *(float4*)(buf + wB + 4) = pB[3];
        __syncthreads();
        float4 upA = make_float4(0.f, 0.f, 0.f, 0.f), upB = upA;
        float4 dnA = upA, dnB = upA;
        if (g > 0)      { upA = *(const float4*)(buf + rU); upB = *(const float4*)(buf + rU + 4); }
        if (g < NB - 1) { dnA = *(const float4*)(buf + rD); dnB = *(const float4*)(buf + rD + 4); }

        float4 poA = upA, poB = upB;
        #pragma unroll
        for (int k = 0; k < 4; ++k) {
            float4 cA = pA[k], cB = pB[k];
            float4 dA = (k < 3) ? pA[k + 1] : dnA;
            float4 dB = (k < 3) ? pB[k + 1] : dnB;
            float lf = __shfl_up(cB.w, 1);
            float rg = __shfl_down(cA.x, 1);
            lf = (c == 0)  ? 0.f : lf;
            rg = (c == 15) ? 0.f : rg;
            float r = rm[k];
            float4 nA, nB;
            nA.x = (poA.x + dA.x + lf   + cA.y) * (f[0] * r);
            nA.y = (poA.y + dA.y + cA.x + cA.z) * (f[1] * r);
            nA.z = (poA.z + dA.z + cA.y + cA.w) * (f[2] * r);
            nA.w = (poA.w + dA.w + cA.z + cB.x) * (f[3] * r);
            nB.x = (poB.x + dB.x + cA.w + cB.y) * (f[4] * r);
            nB.y = (poB.y + dB.y + cB.x + cB.z) * (f[5] * r);
            nB.z = (poB.z + dB.z + cB.y + cB.w) * (f[6] * r);
            nB.w = (poB.w + dB.w + cB.z + rg  ) * (f[7] * r);
            pA[k] = nA; pB[k] = nB;
            poA = cA; poB = cB;
        }
    }

    #pragma unroll
    for (int k = 0; k < 4; ++k) {
        int w = 4 * g + k;
        if (w >= HALO && w < WY - HALO) {
            float* orow = out + (long)(gy0 + w) * N;
            if (c >= 2 && c <= 13) {
                *(float4*)(orow + colb)     = pA[k];
                *(float4*)(orow + colb + 4) = pB[k];
            } else if (c == 1) {
                float2 v; v.x = pA[k].z; v.y = pA[k].w;
                *(float2*)(orow + gx0 + 10) = v;
                *(float4*)(orow + gx0 + 12) = pB[k];
            } else if (c == 14) {
                *(float4*)(orow + colb) = pA[k];
                float2 v; v.x = pB[k].x; v.y = pB[k].y;
                *(float2*)(orow + gx0 + 116) = v;
            }
        }
    }
}

// ---- steady-state launch: load field window, 10 sweeps ----
__global__ __launch_bounds__(NTHR) void jm_sweep(const float* __restrict__ in,
                                                 float* __restrict__ out) {
    __shared__ float bnd[2 * BUFW];
    const int wgid = swz_wgid(blockIdx.x);
    const int bx = wgid % NTX;
    const int by = wgid / NTX;
    const int ox = (bx < NTX - 1) ? bx * TX : (N - TX);
    const int oy = (by < NTY - 1) ? by * TY : (N - TY);
    const int gx0 = ox - HALO, gy0 = oy - HALO;
    const int t = threadIdx.x;
    const int c = t & 15;
    const int g = t >> 4;
    const int colb = gx0 + 8 * c;

    float f[8];
    #pragma unroll
    for (int j = 0; j < 8; ++j)
        f[j] = (colb + j >= 1 && colb + j <= N - 2) ? 0.25f : 0.f;
    float rm[4];
    #pragma unroll
    for (int k = 0; k < 4; ++k) {
        int gr = gy0 + 4 * g + k;
        rm[k] = (gr >= 1 && gr <= N - 2) ? 1.f : 0.f;
    }

    float4 pA[4], pB[4];
    #pragma unroll
    for (int k = 0; k < 4; ++k) {
        int gr = gy0 + 4 * g + k;
        float4 a = make_float4(0.f, 0.f, 0.f, 0.f), b = a;
        if (gr >= 0 && gr < N) {
            const float* row = in + (long)gr * N;
            if (colb >= 0 && colb + 7 < N) {
                a = *(const float4*)(row + colb);
                b = *(const float4*)(row + colb + 4);
            } else {
                float v[8];
                #pragma unroll
                for (int j = 0; j < 8; ++j)
                    v[j] = (colb + j >= 0 && colb + j < N) ? row[colb + j] : 0.f;
                a = make_float4(v[0], v[1], v[2], v[3]);
                b = make_float4(v[4], v[5], v[6], v[7]);
            }
        }
        pA[k] = a; pB[k] = b;
    }

    const int co = 8 * c;
    const int wT = (NB + g) * PS + co;
    const int wB = g * PS + co;
    const int rU = ((g > 0) ? (g - 1) : 0) * PS + co;
    const int rD = (NB + ((g < NB - 1) ? (g + 1) : g)) * PS + co;

    for (int s = 0; s < SWP; ++s) {
        float* buf = bnd + (s & 1) * BUFW;
        *(float4*)(buf + wT)     = pA[0];
        *(float4*)(buf + wT + 4) = pB[0];
        *(float4*)(buf + wB)     = pA[3];
        *(float4*)(buf + wB + 4) = pB[3];
        __syncthreads();
        float4 upA = make_float4(0.f, 0.f, 0.f, 0.f), upB = upA;
        float4 dnA = upA, dnB = upA;
        if (g > 0)      { upA = *(const float4*)(buf + rU); upB = *(const float4*)(buf + rU + 4); }
        if (g < NB - 1) { dnA = *(const float4*)(buf + rD); dnB = *(const float4*)(buf + rD + 4); }

        float4 poA = upA, poB = upB;
        #pragma unroll
        for (int k = 0; k < 4; ++k) {
            float4 cA = pA[k], cB = pB[k];
            float4 dA = (k < 3) ? pA[k + 1] : dnA;
            float4 dB = (k < 3) ? pB[k + 1] : dnB;
            float lf = __shfl_up(cB.w, 1);
            float rg = __shfl_down(cA.x, 1);
            lf = (c == 0)  ? 0.f : lf;
            rg = (c == 15) ? 0.f : rg;
            float r = rm[k];
            float4 nA, nB;
            nA.x = (poA.x + dA.x + lf   + cA.y) * (f[0] * r);
            nA.y = (poA.y + dA.y + cA.x + cA.z) * (f[1] * r);
            nA.z = (poA.z + dA.z + cA.y + cA.w) * (f[2] * r);
            nA.w = (poA.w + dA.w + cA.z + cB.x) * (f[3] * r);
            nB.x = (poB.x + dB.x + cA.w + cB.y) * (f[4] * r);
            nB.y = (poB.y + dB.y + cB.x + cB.z) * (f[5] * r);
            nB.z = (poB.z + dB.z + cB.y + cB.w) * (f[6] * r);
            nB.w = (poB.w + dB.w + cB.z + rg  ) * (f[7] * r);
            pA[k] = nA; pB[k] = nB;
            poA = cA; poB = cB;
        }
    }

    #pragma unroll
    for (int k = 0; k < 4; ++k) {
        int w = 4 * g + k;
        if (w >= HALO && w < WY - HALO) {
            float* orow = out + (long)(gy0 + w) * N;
            if (c >= 2 && c <= 13) {
                *(float4*)(orow + colb)     = pA[k];
                *(float4*)(orow + colb + 4) = pB[k];
            } else if (c == 1) {
                float2 v; v.x = pA[k].z; v.y = pA[k].w;
                *(float2*)(orow + gx0 + 10) = v;
                *(float4*)(orow + gx0 + 12) = pB[k];
            } else if (c == 14) {
                *(float4*)(orow + colb) = pA[k];
                float2 v; v.x = pB[k].x; v.y = pB[k].y;
                *(float2*)(orow + gx0 + 116) = v;
            }
        }
    }
}

extern "C" void kernel_launch(void* const* d_in, const int* in_sizes, int n_in,
                              void* d_out, int out_size, void* d_ws, size_t ws_size,
                              hipStream_t stream) {
    const float* X = (const float*)d_in[0];
    const float* Y = (const float*)d_in[1];
    float* out = (float*)d_out;
    float* ws  = (float*)d_ws;

    // launch 1: init fused + sweeps 1..10 -> ws
    jm_sweep0<<<NTX * NTY, NTHR, 0, stream>>>(X, Y, ws);

    // launches 2..10: sweeps 11..100, ping-pong; 9 launches (odd) -> ends in out
    float* a = ws;
    float* b = out;
    for (int it = 0; it < 9; ++it) {
        jm_sweep<<<NTX * NTY, NTHR, 0, stream>>>(a, b);
        float* tp = a; a = b; b = tp;
    }
}

// Round 23
// 231.681 us; speedup vs baseline: 1.3728x; 1.3728x over previous
//
#include <hip/hip_runtime.h>

#define N      2048
#define HALO   10            // sweeps fused per launch
#define SWP    10
#define WX     128           // window width (16 threads x 8 cols)
#define WY     64            // window rows  (16 bands x 4 rows)
#define TX     108           // output tile width
#define TY     44            // output tile height
#define NTX    19            // last tile clamped; overlap writes identical values
#define NTY    47
#define NTHR   256
#define NB     16            // bands of 4 rows
#define PS     132           // LDS boundary row stride (words)
#define BUFW   (2*NB*PS)     // one slab: 4224 words; two slabs = 33.8 KB
// XCD swizzle (bijective, m204 form): NWG=893, q=111, r=5 -> XCD 0..4 own 112
// consecutive tile-ids, XCD 5..7 own 111. Same mapping every launch => each
// XCD re-reads its own previous writes from its own L2.
#define NWGQ   111
#define NWGR   5

__device__ __forceinline__ float bump(float xv, float yv) {
    float dx = xv - 0.5f, dy = yv - 0.5f;
    return expf(-50.f * (dx * dx + dy * dy));
}

__device__ __forceinline__ int swz_wgid(int bid) {
    int xcd = bid & 7;
    int j   = bid >> 3;
    int start = (xcd < NWGR) ? xcd * (NWGQ + 1)
                             : NWGR * (NWGQ + 1) + (xcd - NWGR) * NWGQ;
    return start + j;
}

// Champion structure (R18/R21, 231.5 µs):
// - 10 launches x 10 fused sweeps, ping-pong ws<->out, init fused in launch 1
// - each thread owns a 4x8 patch in VGPRs; LDS ping-pong slabs hold only
//   band-boundary rows -> 1 barrier/sweep
// - XCD-stripe swizzle keeps inter-launch traffic in each XCD's own L2 (-9%)
// - 256 thr/block, 33.8 KB LDS -> 3.49 blocks/CU, ~14 waves/CU (required:
//   128-thr variant @7 waves/CU +15%, 384-thr tall window @~11% occ +37%)
// - contamination advances 1 cell/sweep; stored cells sit at window distance
//   >= HALO -> exact. Kernels duplicated verbatim (no shared __device__ fn):
//   R8/R9 showed cross-instantiation regalloc coupling costs ~30%.

// ---- first launch: init fused (patch = exp bump from X,Y), then 10 sweeps ----
__global__ __launch_bounds__(NTHR) void jm_sweep0(const float* __restrict__ X,
                                                  const float* __restrict__ Y,
                                                  float* __restrict__ out) {
    __shared__ float bnd[2 * BUFW];
    const int wgid = swz_wgid(blockIdx.x);
    const int bx = wgid % NTX;
    const int by = wgid / NTX;
    const int ox = (bx < NTX - 1) ? bx * TX : (N - TX);
    const int oy = (by < NTY - 1) ? by * TY : (N - TY);
    const int gx0 = ox - HALO, gy0 = oy - HALO;
    const int t = threadIdx.x;
    const int c = t & 15;
    const int g = t >> 4;
    const int colb = gx0 + 8 * c;

    float f[8];
    #pragma unroll
    for (int j = 0; j < 8; ++j)
        f[j] = (colb + j >= 1 && colb + j <= N - 2) ? 0.25f : 0.f;
    float rm[4];
    #pragma unroll
    for (int k = 0; k < 4; ++k) {
        int gr = gy0 + 4 * g + k;
        rm[k] = (gr >= 1 && gr <= N - 2) ? 1.f : 0.f;
    }

    // ---- init patch directly from X,Y (out-of-domain -> 0) ----
    float4 pA[4], pB[4];
    #pragma unroll
    for (int k = 0; k < 4; ++k) {
        int gr = gy0 + 4 * g + k;
        float4 a = make_float4(0.f, 0.f, 0.f, 0.f), b = a;
        if (gr >= 0 && gr < N) {
            const float* xr = X + (long)gr * N;
            const float* yr = Y + (long)gr * N;
            if (colb >= 0 && colb + 7 < N) {
                float4 x0 = *(const float4*)(xr + colb);
                float4 x1 = *(const float4*)(xr + colb + 4);
                float4 y0 = *(const float4*)(yr + colb);
                float4 y1 = *(const float4*)(yr + colb + 4);
                a.x = bump(x0.x, y0.x); a.y = bump(x0.y, y0.y);
                a.z = bump(x0.z, y0.z); a.w = bump(x0.w, y0.w);
                b.x = bump(x1.x, y1.x); b.y = bump(x1.y, y1.y);
                b.z = bump(x1.z, y1.z); b.w = bump(x1.w, y1.w);
            } else {
                float v[8];
                #pragma unroll
                for (int j = 0; j < 8; ++j) {
                    int gc = colb + j;
                    v[j] = (gc >= 0 && gc < N) ? bump(xr[gc], yr[gc]) : 0.f;
                }
                a = make_float4(v[0], v[1], v[2], v[3]);
                b = make_float4(v[4], v[5], v[6], v[7]);
            }
        }
        pA[k] = a; pB[k] = b;
    }

    const int co = 8 * c;
    const int wT = (NB + g) * PS + co;
    const int wB = g * PS + co;
    const int rU = ((g > 0) ? (g - 1) : 0) * PS + co;
    const int rD = (NB + ((g < NB - 1) ? (g + 1) : g)) * PS + co;

    for (int s = 0; s < SWP; ++s) {
        float* buf = bnd + (s & 1) * BUFW;
        *(float4*)(buf + wT)     = pA[0];
        *(float4*)(buf + wT + 4) = pB[0];
        *(float4*)(buf + wB)     = pA[3];
        *(float4*)(buf + wB + 4) = pB[3];
        __syncthreads();
        float4 upA = make_float4(0.f, 0.f, 0.f, 0.f), upB = upA;
        float4 dnA = upA, dnB = upA;
        if (g > 0)      { upA = *(const float4*)(buf + rU); upB = *(const float4*)(buf + rU + 4); }
        if (g < NB - 1) { dnA = *(const float4*)(buf + rD); dnB = *(const float4*)(buf + rD + 4); }

        float4 poA = upA, poB = upB;
        #pragma unroll
        for (int k = 0; k < 4; ++k) {
            float4 cA = pA[k], cB = pB[k];
            float4 dA = (k < 3) ? pA[k + 1] : dnA;
            float4 dB = (k < 3) ? pB[k + 1] : dnB;
            float lf = __shfl_up(cB.w, 1);
            float rg = __shfl_down(cA.x, 1);
            lf = (c == 0)  ? 0.f : lf;
            rg = (c == 15) ? 0.f : rg;
            float r = rm[k];
            float4 nA, nB;
            nA.x = (poA.x + dA.x + lf   + cA.y) * (f[0] * r);
            nA.y = (poA.y + dA.y + cA.x + cA.z) * (f[1] * r);
            nA.z = (poA.z + dA.z + cA.y + cA.w) * (f[2] * r);
            nA.w = (poA.w + dA.w + cA.z + cB.x) * (f[3] * r);
            nB.x = (poB.x + dB.x + cA.w + cB.y) * (f[4] * r);
            nB.y = (poB.y + dB.y + cB.x + cB.z) * (f[5] * r);
            nB.z = (poB.z + dB.z + cB.y + cB.w) * (f[6] * r);
            nB.w = (poB.w + dB.w + cB.z + rg  ) * (f[7] * r);
            pA[k] = nA; pB[k] = nB;
            poA = cA; poB = cB;
        }
    }

    #pragma unroll
    for (int k = 0; k < 4; ++k) {
        int w = 4 * g + k;
        if (w >= HALO && w < WY - HALO) {
            float* orow = out + (long)(gy0 + w) * N;
            if (c >= 2 && c <= 13) {
                *(float4*)(orow + colb)     = pA[k];
                *(float4*)(orow + colb + 4) = pB[k];
            } else if (c == 1) {
                float2 v; v.x = pA[k].z; v.y = pA[k].w;
                *(float2*)(orow + gx0 + 10) = v;
                *(float4*)(orow + gx0 + 12) = pB[k];
            } else if (c == 14) {
                *(float4*)(orow + colb) = pA[k];
                float2 v; v.x = pB[k].x; v.y = pB[k].y;
                *(float2*)(orow + gx0 + 116) = v;
            }
        }
    }
}

// ---- steady-state launch: load field window, 10 sweeps ----
__global__ __launch_bounds__(NTHR) void jm_sweep(const float* __restrict__ in,
                                                 float* __restrict__ out) {
    __shared__ float bnd[2 * BUFW];
    const int wgid = swz_wgid(blockIdx.x);
    const int bx = wgid % NTX;
    const int by = wgid / NTX;
    const int ox = (bx < NTX - 1) ? bx * TX : (N - TX);
    const int oy = (by < NTY - 1) ? by * TY : (N - TY);
    const int gx0 = ox - HALO, gy0 = oy - HALO;
    const int t = threadIdx.x;
    const int c = t & 15;
    const int g = t >> 4;
    const int colb = gx0 + 8 * c;

    float f[8];
    #pragma unroll
    for (int j = 0; j < 8; ++j)
        f[j] = (colb + j >= 1 && colb + j <= N - 2) ? 0.25f : 0.f;
    float rm[4];
    #pragma unroll
    for (int k = 0; k < 4; ++k) {
        int gr = gy0 + 4 * g + k;
        rm[k] = (gr >= 1 && gr <= N - 2) ? 1.f : 0.f;
    }

    float4 pA[4], pB[4];
    #pragma unroll
    for (int k = 0; k < 4; ++k) {
        int gr = gy0 + 4 * g + k;
        float4 a = make_float4(0.f, 0.f, 0.f, 0.f), b = a;
        if (gr >= 0 && gr < N) {
            const float* row = in + (long)gr * N;
            if (colb >= 0 && colb + 7 < N) {
                a = *(const float4*)(row + colb);
                b = *(const float4*)(row + colb + 4);
            } else {
                float v[8];
                #pragma unroll
                for (int j = 0; j < 8; ++j)
                    v[j] = (colb + j >= 0 && colb + j < N) ? row[colb + j] : 0.f;
                a = make_float4(v[0], v[1], v[2], v[3]);
                b = make_float4(v[4], v[5], v[6], v[7]);
            }
        }
        pA[k] = a; pB[k] = b;
    }

    const int co = 8 * c;
    const int wT = (NB + g) * PS + co;
    const int wB = g * PS + co;
    const int rU = ((g > 0) ? (g - 1) : 0) * PS + co;
    const int rD = (NB + ((g < NB - 1) ? (g + 1) : g)) * PS + co;

    for (int s = 0; s < SWP; ++s) {
        float* buf = bnd + (s & 1) * BUFW;
        *(float4*)(buf + wT)     = pA[0];
        *(float4*)(buf + wT + 4) = pB[0];
        *(float4*)(buf + wB)     = pA[3];
        *(float4*)(buf + wB + 4) = pB[3];
        __syncthreads();
        float4 upA = make_float4(0.f, 0.f, 0.f, 0.f), upB = upA;
        float4 dnA = upA, dnB = upA;
        if (g > 0)      { upA = *(const float4*)(buf + rU); upB = *(const float4*)(buf + rU + 4); }
        if (g < NB - 1) { dnA = *(const float4*)(buf + rD); dnB = *(const float4*)(buf + rD + 4); }

        float4 poA = upA, poB = upB;
        #pragma unroll
        for (int k = 0; k < 4; ++k) {
            float4 cA = pA[k], cB = pB[k];
            float4 dA = (k < 3) ? pA[k + 1] : dnA;
            float4 dB = (k < 3) ? pB[k + 1] : dnB;
            float lf = __shfl_up(cB.w, 1);
            float rg = __shfl_down(cA.x, 1);
            lf = (c == 0)  ? 0.f : lf;
            rg = (c == 15) ? 0.f : rg;
            float r = rm[k];
            float4 nA, nB;
            nA.x = (poA.x + dA.x + lf   + cA.y) * (f[0] * r);
            nA.y = (poA.y + dA.y + cA.x + cA.z) * (f[1] * r);
            nA.z = (poA.z + dA.z + cA.y + cA.w) * (f[2] * r);
            nA.w = (poA.w + dA.w + cA.z + cB.x) * (f[3] * r);
            nB.x = (poB.x + dB.x + cA.w + cB.y) * (f[4] * r);
            nB.y = (poB.y + dB.y + cB.x + cB.z) * (f[5] * r);
            nB.z = (poB.z + dB.z + cB.y + cB.w) * (f[6] * r);
            nB.w = (poB.w + dB.w + cB.z + rg  ) * (f[7] * r);
            pA[k] = nA; pB[k] = nB;
            poA = cA; poB = cB;
        }
    }

    #pragma unroll
    for (int k = 0; k < 4; ++k) {
        int w = 4 * g + k;
        if (w >= HALO && w < WY - HALO) {
            float* orow = out + (long)(gy0 + w) * N;
            if (c >= 2 && c <= 13) {
                *(float4*)(orow + colb)     = pA[k];
                *(float4*)(orow + colb + 4) = pB[k];
            } else if (c == 1) {
                float2 v; v.x = pA[k].z; v.y = pA[k].w;
                *(float2*)(orow + gx0 + 10) = v;
                *(float4*)(orow + gx0 + 12) = pB[k];
            } else if (c == 14) {
                *(float4*)(orow + colb) = pA[k];
                float2 v; v.x = pB[k].x; v.y = pB[k].y;
                *(float2*)(orow + gx0 + 116) = v;
            }
        }
    }
}

extern "C" void kernel_launch(void* const* d_in, const int* in_sizes, int n_in,
                              void* d_out, int out_size, void* d_ws, size_t ws_size,
                              hipStream_t stream) {
    const float* X = (const float*)d_in[0];
    const float* Y = (const float*)d_in[1];
    float* out = (float*)d_out;
    float* ws  = (float*)d_ws;

    // launch 1: init fused + sweeps 1..10 -> ws
    jm_sweep0<<<NTX * NTY, NTHR, 0, stream>>>(X, Y, ws);

    // launches 2..10: sweeps 11..100, ping-pong; 9 launches (odd) -> ends in out
    float* a = ws;
    float* b = out;
    for (int it = 0; it < 9; ++it) {
        jm_sweep<<<NTX * NTY, NTHR, 0, stream>>>(a, b);
        float* tp = a; a = b; b = tp;
    }
}